// Round 1
// baseline (116.996 us; speedup 1.0000x reference)
//
#include <hip/hip_runtime.h>

// ContrastiveLoss on MI355X (gfx950), B=8192, D=128, labels in [0,2048).
// loss = -(1/cnt) sum_{i: P_i>0} [ S_i/P_i - M - ln Z_i ]
//   Z_i = sum_{j != i} exp(sim_ij - M),  sim = E E^T / T,  M = 1/T (valid shift).
//   S_i = (e_i . g_{lab_i} - e_i . e_i) / T  with fp32 class sums g_c.
//   P_i = count[lab_i] - 1.
// R12: (a) main switched to mfma_f32_32x32x16_bf16 (64 MFMA/wave vs 128,
//      2382 vs 2075 TF ceiling); (b) 4-chunk (64-col) async staging via
//      global_load_lds w/ pre-swizzled GLOBAL source (linear LDS dest,
//      same verified conflict-free XOR read layout), raw s_barrier +
//      counted s_waitcnt vmcnt(4) so next chunk's loads fly under compute
//      (__syncthreads would drain vmcnt(0) and kill the overlap);
//      (c) finalize2 fused into finalize1 via device-scope ticket.
// Kept: plain __launch_bounds__(256) on main (R3/R7/R10: min-waves pinning
//      forces the VGPR/AGPR split-spill).

#define BATCH 8192
#define DIMK  128
#define INV_T 14.285714285714286f
#define MSUB  14.285714285714286f
#define K1    20.609929155311264f   // INV_T * log2(e)
#define K2    20.609929155311264f   // MSUB  * log2(e)

typedef short bf16x8 __attribute__((ext_vector_type(8)));
typedef float f32x16 __attribute__((ext_vector_type(16)));

__device__ __forceinline__ unsigned short f2bf_rne(float f) {
    unsigned u = __float_as_uint(f);
    u += 0x7FFFu + ((u >> 16) & 1u);
    return (unsigned short)(u >> 16);
}
__device__ __forceinline__ float bf2f(unsigned short b) {
    return __uint_as_float(((unsigned)b) << 16);
}

// width-16 global->LDS direct load; LDS dest is wave-uniform base + lane*16.
__device__ __forceinline__ void gload16(const ushort* g, ushort* l) {
    __builtin_amdgcn_global_load_lds(
        (const __attribute__((address_space(1))) void*)g,
        (__attribute__((address_space(3))) void*)l, 16, 0, 0);
}

// ---------------------------------------------------------------------------
// Prep: blocks [0,1024): fp32->bf16 cvt (4 elems/thread) + zero the Z-partial
//       region (zpartR 1 MB + zcol 32 KB = 67584 float4s).
//       blocks [1024,1536): class sums, 1 class per wave, labels staged in LDS.
__global__ __launch_bounds__(256) void
prep_kernel(const float* __restrict__ emb, const int* __restrict__ labels,
            ushort* __restrict__ Ebf, float* __restrict__ gsum, int* __restrict__ gcnt,
            float4* __restrict__ zzero, int* __restrict__ ticket) {
    if (blockIdx.x < 1024) {
        if (blockIdx.x == 0 && threadIdx.x == 0) *ticket = 0;
        int i = blockIdx.x * 256 + threadIdx.x;
        if (i < 67584) {
            float4 z = {0.f, 0.f, 0.f, 0.f};
            zzero[i] = z;
        }
        float4 v = ((const float4*)emb)[i];
        ushort4 o;
        o.x = f2bf_rne(v.x); o.y = f2bf_rne(v.y);
        o.z = f2bf_rne(v.z); o.w = f2bf_rne(v.w);
        ((ushort4*)Ebf)[i] = o;
    } else {
        __shared__ int labs[BATCH];           // 32 KB
        const int tid = threadIdx.x;
#pragma unroll
        for (int it = 0; it < 8; ++it)
            ((int4*)labs)[it * 256 + tid] = ((const int4*)labels)[it * 256 + tid];
        __syncthreads();

        const int lane = tid & 63;
        const int wid  = tid >> 6;
        const int c    = (blockIdx.x - 1024) * 4 + wid;   // class id [0,2048)
        float2 acc = {0.f, 0.f};
        int cnt = 0;
        int nl = labs[lane];
        for (int j0 = 0; j0 < BATCH; j0 += 64) {
            int cur = nl;
            int nidx = j0 + 64 < BATCH ? j0 + 64 : 0;
            nl = labs[nidx + lane];
            unsigned long long m = __ballot(cur == c);
            cnt += __popcll(m);
            while (m) {
                int j = __ffsll(m) - 1;
                m &= m - 1;
                float2 v = *(const float2*)(emb + (size_t)(j0 + j) * DIMK + lane * 2);
                acc.x += v.x; acc.y += v.y;
            }
        }
        *(float2*)(gsum + (size_t)c * DIMK + lane * 2) = acc;
        if (lane == 0) gcnt[c] = cnt;
    }
}

// ---------------------------------------------------------------------------
// Main: Z partials over the upper triangle. Grid 1056 = 528 macro-tiles x 2
// row-halves, block 256 (4 waves). Macro-tile (ti,tj), tj>=ti; this block
// covers rows [ti*256 + half*128, +128) x cols [tj*256, +256).
// Cols staged in four 64-col chunks, double-buffered 2x16KB, via
// global_load_lds (linear LDS dest, pre-swizzled global source).
// LDS layout per chunk: 16B unit for (colLocal,c) at
//   u = (colLocal>>4)*256 + c*16 + ((colLocal&15)^c)   (conflict-free reads,
//   verified SQ_LDS_BANK_CONFLICT=0 for this XOR family in R10).
// Wave owns 32 rows via one 32x32x16 MFMA tile; acc f32x16, C/D layout
//   col=lane&31, row=(r&3)+8*(r>>2)+4*(lane>>5).
__global__ __launch_bounds__(256) void
contrastive_main(const ushort* __restrict__ Ebf, float* __restrict__ zpartR,
                 float* __restrict__ zcol) {
    __shared__ __align__(16) ushort Bs[2][1024 * 8];  // 2 x 16 KB
    __shared__ float cpart[4][256];                   // 4 KB
    const int tid  = threadIdx.x;
    const int lane = tid & 63;
    const int wid  = tid >> 6;
    const int l32  = lane & 31;
    const int hi   = lane >> 5;

    // block -> (ti, tj, half)
    int b = blockIdx.x >> 1;
    const int half = blockIdx.x & 1;
    int ti = 0;
    while (b >= 32 - ti) { b -= 32 - ti; ++ti; }
    const int tj = ti + b;
    const int row_base = ti * 256 + half * 128 + wid * 32;
    const int col_tile = tj * 256;

    // A fragments: 32 rows x K=128. A-lane row = l32, k = kk*16 + hi*8 + i.
    // Issued FIRST so the compiler's afrag wait is vmcnt(8), not vmcnt(0).
    bf16x8 afrag[8];
#pragma unroll
    for (int kk = 0; kk < 8; ++kk)
        afrag[kk] = *(const bf16x8*)(Ebf + (size_t)(row_base + l32) * DIMK
                                     + kk * 16 + hi * 8);

    // Per-thread staging sources: linear LDS unit u = it*256 + tid holds
    // (colLocal = (u>>8)*16 + ((u&15)^c), c = (u>>4)&15).
    const ushort* gsrc[4];
#pragma unroll
    for (int it = 0; it < 4; ++it) {
        const int u = it * 256 + tid;
        const int g = u >> 8, c = (u >> 4) & 15, x = u & 15;
        gsrc[it] = Ebf + (size_t)(col_tile + g * 16 + (x ^ c)) * DIMK + c * 8;
    }

    float zacc[16];
#pragma unroll
    for (int r = 0; r < 16; ++r) zacc[r] = 0.f;

#define STAGE_CHUNK(K, BUF)                                                   \
    {                                                                         \
        _Pragma("unroll")                                                     \
        for (int it = 0; it < 4; ++it)                                        \
            gload16(gsrc[it] + (K) * 64 * DIMK,                               \
                    &Bs[BUF][(it * 256 + wid * 64) * 8]);                     \
    }

#define COMPUTE_CHUNK(BUF, CB)                                                \
    {                                                                         \
        const ushort* bs = &Bs[BUF][0];                                       \
        _Pragma("unroll")                                                     \
        for (int nt = 0; nt < 2; ++nt) {                                      \
            const int colL = nt * 32 + l32;                                   \
            const int gp = (colL >> 4) * 256;                                 \
            const int x0 = colL & 15;                                         \
            bf16x8 bfrag[8];                                                  \
            _Pragma("unroll")                                                 \
            for (int kk = 0; kk < 8; ++kk) {                                  \
                const int c = kk * 2 + hi;                                    \
                bfrag[kk] = *(const bf16x8*)&bs[(size_t)(gp + c * 16 + (x0 ^ c)) * 8]; \
            }                                                                 \
            f32x16 acc;                                                       \
            _Pragma("unroll")                                                 \
            for (int r = 0; r < 16; ++r) acc[r] = 0.f;                        \
            _Pragma("unroll")                                                 \
            for (int kk = 0; kk < 8; ++kk)                                    \
                acc = __builtin_amdgcn_mfma_f32_32x32x16_bf16(afrag[kk], bfrag[kk], acc, 0, 0, 0); \
            float csum = 0.f;                                                 \
            _Pragma("unroll")                                                 \
            for (int r = 0; r < 16; ++r) {                                    \
                float e = __builtin_amdgcn_exp2f(__builtin_fmaf(acc[r], K1, -K2)); \
                zacc[r] += e; csum += e;                                      \
            }                                                                 \
            csum += __shfl_xor(csum, 32, 64);                                 \
            if (hi == 0) cpart[wid][(CB) + nt * 32 + l32] = csum;             \
        }                                                                     \
    }

    // 4-chunk pipeline, 2 buffers. vmcnt counts this wave's own staging
    // instructions only (no other VMEM in the loop body): after issuing the
    // next chunk's 4 loads, vmcnt(4) == "previous chunk's 4 have landed".
    STAGE_CHUNK(0, 0);
    STAGE_CHUNK(1, 1);
    asm volatile("s_waitcnt vmcnt(4)" ::: "memory");
    __builtin_amdgcn_s_barrier();
    COMPUTE_CHUNK(0, 0);
    __builtin_amdgcn_s_barrier();          // all waves done reading buf0
    STAGE_CHUNK(2, 0);
    asm volatile("s_waitcnt vmcnt(4)" ::: "memory");
    __builtin_amdgcn_s_barrier();          // chunk1 visible everywhere
    COMPUTE_CHUNK(1, 64);
    __builtin_amdgcn_s_barrier();
    STAGE_CHUNK(3, 1);
    asm volatile("s_waitcnt vmcnt(4)" ::: "memory");
    __builtin_amdgcn_s_barrier();
    COMPUTE_CHUNK(0, 128);
    asm volatile("s_waitcnt vmcnt(0)" ::: "memory");
    __builtin_amdgcn_s_barrier();
    COMPUTE_CHUNK(1, 192);

#undef STAGE_CHUNK
#undef COMPUTE_CHUNK

    // Row partials: zacc[r] holds (row = (r&3)+8*(r>>2)+4*hi, col = l32)
    // partial; reduce across the 32 col-lanes of the half.
#pragma unroll
    for (int r = 0; r < 16; ++r) {
        float z = zacc[r];
#pragma unroll
        for (int m = 1; m <= 16; m <<= 1) z += __shfl_xor(z, m, 64);
        if (l32 == 0) {
            int row = row_base + (r & 3) + 8 * (r >> 2) + 4 * hi;
            zpartR[(size_t)tj * BATCH + row] = z;
        }
    }

    // Col partials: combine the 4 waves, one distributed atomic per column.
    __syncthreads();
    if (ti != tj) {
        float s = cpart[0][tid] + cpart[1][tid] + cpart[2][tid] + cpart[3][tid];
        atomicAdd(&zcol[tj * 256 + tid], s);
    }
}

// ---------------------------------------------------------------------------
// Finalize: 512 blocks x 256 (4 waves); each wave processes 4 rows.
// Per row: lane l covers dims 2l,2l+1; lanes 0..31 read zpartR, lane 32 zcol.
// Fused tail (R12): device-scope ticket; last block reduces the 512 partials.
__global__ __launch_bounds__(256) void
finalize1(const float* __restrict__ emb, const ushort* __restrict__ Ebf,
          const int* __restrict__ labels, const float* __restrict__ gsum,
          const int* __restrict__ gcnt, const float* __restrict__ zpartR,
          const float* __restrict__ zcol,
          float* __restrict__ bpart, int* __restrict__ bcnt,
          int* __restrict__ ticket, float* __restrict__ out) {
    __shared__ float sf[4];
    __shared__ int   si[4];
    __shared__ int   lastflag;
    const int lane = threadIdx.x & 63;
    const int wid  = threadIdx.x >> 6;

    float wsum = 0.f;
    int   wcnt = 0;
#pragma unroll
    for (int it = 0; it < 4; ++it) {
        const int r   = blockIdx.x * 16 + wid * 4 + it;
        const int lab = labels[r];
        const int P   = gcnt[lab] - 1;

        float2 ev = *(const float2*)(emb  + (size_t)r   * DIMK + lane * 2);
        float2 gv = *(const float2*)(gsum + (size_t)lab * DIMK + lane * 2);
        unsigned bb = *(const unsigned*)(Ebf + (size_t)r * DIMK + lane * 2);
        float b0 = bf2f((unsigned short)(bb & 0xFFFF));
        float b1 = bf2f((unsigned short)(bb >> 16));

        float dotg = ev.x * gv.x + ev.y * gv.y;
        float ssd  = ev.x * ev.x + ev.y * ev.y;
        float sdbf = b0 * b0 + b1 * b1;
        float Z = 0.f;
        if (lane < 32)       Z = zpartR[(size_t)lane * BATCH + r];
        else if (lane == 32) Z = zcol[r];

#pragma unroll
        for (int m = 1; m <= 32; m <<= 1) {
            dotg += __shfl_xor(dotg, m, 64);
            ssd  += __shfl_xor(ssd,  m, 64);
            sdbf += __shfl_xor(sdbf, m, 64);
            Z    += __shfl_xor(Z,    m, 64);
        }
        Z -= __builtin_amdgcn_exp2f(__builtin_fmaf(sdbf, K1, -K2));  // remove diagonal

        const bool has = (P > 0);
        wsum += has ? ((dotg - ssd) * INV_T / (float)P - MSUB - __logf(Z)) : 0.f;
        wcnt += has ? 1 : 0;
    }

    if (lane == 0) { sf[wid] = wsum; si[wid] = wcnt; }
    __syncthreads();
    if (threadIdx.x == 0) {
        bpart[blockIdx.x] = sf[0] + sf[1] + sf[2] + sf[3];
        bcnt [blockIdx.x] = si[0] + si[1] + si[2] + si[3];
        __threadfence();                               // release partials
        lastflag = (atomicAdd(ticket, 1) == (int)gridDim.x - 1);
    }
    __syncthreads();
    if (lastflag) {                                    // block-uniform branch
        __threadfence();                               // acquire others' partials
        const int t = threadIdx.x;
        float v = bpart[t] + bpart[t + 256];
        int   c = bcnt[t]  + bcnt[t + 256];
#pragma unroll
        for (int m = 1; m <= 32; m <<= 1) {
            v += __shfl_xor(v, m, 64);
            c += __shfl_xor(c, m, 64);
        }
        if ((t & 63) == 0) { sf[t >> 6] = v; si[t >> 6] = c; }
        __syncthreads();
        if (t == 0) {
            float tot = sf[0] + sf[1] + sf[2] + sf[3];
            int cc = si[0] + si[1] + si[2] + si[3];
            out[0] = -tot / (float)(cc > 0 ? cc : 1);
        }
    }
}

extern "C" void kernel_launch(void* const* d_in, const int* in_sizes, int n_in,
                              void* d_out, int out_size, void* d_ws, size_t ws_size,
                              hipStream_t stream) {
    const float* emb  = (const float*)d_in[0];
    const int* labels = (const int*)d_in[1];
    float* out        = (float*)d_out;

    char* ws = (char*)d_ws;
    ushort* Ebf    = (ushort*)ws;                         // 2 MB  (8192*128*2)
    float*  zpartR = (float*)(ws + (2u << 20));           // 1 MB  (32*8192*4)
    float*  zcol   = (float*)(ws + (3u << 20));           // 32 KB (8192*4)
    float*  gsum   = (float*)(ws + (4u << 20));           // 1 MB  (2048*128*4)
    int*    gcnt   = (int*)  (ws + (5u << 20));           // 8 KB
    float*  bpart  = (float*)(ws + (5u << 20) + 8192);    // 8 KB
    int*    bcnt   = (int*)  (ws + (5u << 20) + 16384);   // 8 KB
    int*    ticket = (int*)  (ws + (5u << 20) + 24576);   // 4 B

    prep_kernel<<<1536, 256, 0, stream>>>(emb, labels, Ebf, gsum, gcnt,
                                          (float4*)zpartR, ticket);
    contrastive_main<<<1056, 256, 0, stream>>>(Ebf, zpartR, zcol);
    finalize1<<<512, 256, 0, stream>>>(emb, Ebf, labels, gsum, gcnt, zpartR, zcol,
                                       bpart, bcnt, ticket, out);
}